// Round 1
// baseline (790.048 us; speedup 1.0000x reference)
//
#include <hip/hip_runtime.h>
#include <cstdint>
#include <cstddef>

#define NN 100000
#define NE 1600000
#define FIN 128
#define HD 64
#define NC 40

// ---------------- setup kernels ----------------

__global__ void k_init(float* deg, int* cnt, int* cur) {
    int i = blockIdx.x * 256 + threadIdx.x;
    if (i < NN) { deg[i] = 1.0f; cnt[i] = 0; cur[i] = 0; }
}

__global__ void k_count(const int* __restrict__ ei, const float* __restrict__ ew,
                        float* deg, int* cnt) {
    int e = blockIdx.x * 256 + threadIdx.x;
    if (e < NE) {
        int c = ei[NE + e];
        atomicAdd(&deg[c], ew[e]);
        atomicAdd(&cnt[c], 1);
    }
}

__global__ void k_dinv(float* deg) {
    int i = blockIdx.x * 256 + threadIdx.x;
    if (i < NN) {
        float d = deg[i];          // deg >= 1 always (self-loop weight 1)
        deg[i] = rsqrtf(d);
    }
}

// single-block exclusive scan over NN counts -> off[NN+1]
__global__ void k_scan(const int* __restrict__ cnt, int* __restrict__ off) {
    __shared__ int sd[1024];
    __shared__ int carry_s;
    int tid = threadIdx.x;
    if (tid == 0) carry_s = 0;
    __syncthreads();
    for (int base = 0; base < NN; base += 1024) {
        int i = base + tid;
        int v = (i < NN) ? cnt[i] : 0;
        sd[tid] = v;
        __syncthreads();
        for (int s = 1; s < 1024; s <<= 1) {
            int t = (tid >= s) ? sd[tid - s] : 0;
            __syncthreads();
            sd[tid] += t;
            __syncthreads();
        }
        int carry = carry_s;
        if (i < NN) off[i] = carry + sd[tid] - v;   // exclusive
        int tot = sd[1023];
        __syncthreads();
        if (tid == 0) carry_s = carry + tot;
        __syncthreads();
    }
    if (tid == 0) off[NN] = carry_s;
}

__global__ void k_fill(const int* __restrict__ ei, const float* __restrict__ ew,
                       const float* __restrict__ dinv, const int* __restrict__ off,
                       int* cur, int* __restrict__ csr_row, float* __restrict__ csr_norm) {
    int e = blockIdx.x * 256 + threadIdx.x;
    if (e < NE) {
        int r = ei[e], c = ei[NE + e];
        float nv = dinv[r] * ew[e] * dinv[c];
        int pos = atomicAdd(&cur[c], 1);
        int slot = off[c] + pos;
        csr_row[slot] = r;
        csr_norm[slot] = nv;
    }
}

// ---------------- dense layers ----------------

// h = relu(x @ W + b): [NN,128] @ [128,64]; W column held in registers per lane
__launch_bounds__(256)
__global__ void k_lin1(const float* __restrict__ x, const float* __restrict__ W,
                       const float* __restrict__ b, float* __restrict__ out) {
    __shared__ __align__(16) float xs[4 * FIN];     // 4 node rows
    int lane = threadIdx.x & 63;
    int sub  = threadIdx.x >> 6;
    float wrs[FIN];
    #pragma unroll
    for (int k = 0; k < FIN; k++) wrs[k] = W[k * HD + lane];
    float bias = b[lane];
    const int nchunk = NN / 4;
    for (int chunk = blockIdx.x; chunk < nchunk; chunk += gridDim.x) {
        int node0 = chunk * 4;
        __syncthreads();
        if (threadIdx.x < 128)
            ((float4*)xs)[threadIdx.x] =
                ((const float4*)(x + (size_t)node0 * FIN))[threadIdx.x];
        __syncthreads();
        float acc = bias;
        const float4* xv4 = (const float4*)(xs + sub * FIN);
        #pragma unroll
        for (int k = 0; k < FIN / 4; k++) {
            float4 xv = xv4[k];
            acc += xv.x * wrs[4*k] + xv.y * wrs[4*k+1] + xv.z * wrs[4*k+2] + xv.w * wrs[4*k+3];
        }
        out[(size_t)(node0 + sub) * HD + lane] = fmaxf(acc, 0.f);
    }
}

// out = A @ W (no bias): [NN,64] @ [64,64]
__launch_bounds__(256)
__global__ void k_mm64(const float* __restrict__ A, const float* __restrict__ W,
                       float* __restrict__ out) {
    __shared__ __align__(16) float xs[4 * HD];
    int lane = threadIdx.x & 63;
    int sub  = threadIdx.x >> 6;
    float wrs[HD];
    #pragma unroll
    for (int k = 0; k < HD; k++) wrs[k] = W[k * HD + lane];
    const int nchunk = NN / 4;
    for (int chunk = blockIdx.x; chunk < nchunk; chunk += gridDim.x) {
        int node0 = chunk * 4;
        __syncthreads();
        if (threadIdx.x < 64)
            ((float4*)xs)[threadIdx.x] =
                ((const float4*)(A + (size_t)node0 * HD))[threadIdx.x];
        __syncthreads();
        float acc = 0.f;
        const float4* xv4 = (const float4*)(xs + sub * HD);
        #pragma unroll
        for (int k = 0; k < HD / 4; k++) {
            float4 xv = xv4[k];
            acc += xv.x * wrs[4*k] + xv.y * wrs[4*k+1] + xv.z * wrs[4*k+2] + xv.w * wrs[4*k+3];
        }
        out[(size_t)(node0 + sub) * HD + lane] = acc;
    }
}

// out = relu(Ahat @ Bm + bias): one wave per node, lane = feature
__global__ void k_agg(const float* __restrict__ Bm, const int* __restrict__ off,
                      const int* __restrict__ csr_row, const float* __restrict__ csr_norm,
                      const float* __restrict__ dinv, const float* __restrict__ bias,
                      float* __restrict__ outp) {
    int node = blockIdx.x * 4 + (threadIdx.x >> 6);
    int lane = threadIdx.x & 63;
    if (node >= NN) return;
    int s = off[node], e = off[node + 1];
    float di = dinv[node];
    float acc = di * di * Bm[(size_t)node * HD + lane];   // self-loop term
    int j = s;
    for (; j + 1 < e; j += 2) {
        int   r0 = csr_row[j],  r1 = csr_row[j + 1];
        float n0 = csr_norm[j], n1 = csr_norm[j + 1];
        acc += n0 * Bm[(size_t)r0 * HD + lane] + n1 * Bm[(size_t)r1 * HD + lane];
    }
    if (j < e) acc += csr_norm[j] * Bm[(size_t)csr_row[j] * HD + lane];
    outp[(size_t)node * HD + lane] = fmaxf(acc + bias[lane], 0.f);
}

// logits = H @ Wo + bo ; out = log_softmax(logits)
__launch_bounds__(256)
__global__ void k_out(const float* __restrict__ Hm, const float* __restrict__ W,
                      const float* __restrict__ b, float* __restrict__ outp) {
    __shared__ float Wl[HD * NC];
    __shared__ __align__(16) float hs[4 * HD];
    int lane = threadIdx.x & 63;
    int sub  = threadIdx.x >> 6;
    for (int i = threadIdx.x; i < HD * NC; i += 256) Wl[i] = W[i];
    int node0 = blockIdx.x * 4;
    if (threadIdx.x < 64)
        ((float4*)hs)[threadIdx.x] =
            ((const float4*)(Hm + (size_t)node0 * HD))[threadIdx.x];
    __syncthreads();
    float logit = -1e30f;
    if (lane < NC) {
        float acc = b[lane];
        #pragma unroll
        for (int k = 0; k < HD; k++) acc += hs[sub * HD + k] * Wl[k * NC + lane];
        logit = acc;
    }
    float m = logit;
    #pragma unroll
    for (int s = 32; s > 0; s >>= 1) m = fmaxf(m, __shfl_xor(m, s));
    float ex = (lane < NC) ? expf(logit - m) : 0.f;
    float sum = ex;
    #pragma unroll
    for (int s = 32; s > 0; s >>= 1) sum += __shfl_xor(sum, s);
    if (lane < NC) outp[(size_t)node0 * NC + sub * NC + lane] = (logit - m) - logf(sum);
}

// ---------------- launch ----------------

extern "C" void kernel_launch(void* const* d_in, const int* in_sizes, int n_in,
                              void* d_out, int out_size, void* d_ws, size_t ws_size,
                              hipStream_t stream) {
    const float* x   = (const float*)d_in[0];
    const int*   ei  = (const int*)  d_in[1];
    const float* ew  = (const float*)d_in[2];
    const float* Wf  = (const float*)d_in[3];
    const float* bf  = (const float*)d_in[4];
    const float* Wc1 = (const float*)d_in[5];
    const float* bc1 = (const float*)d_in[6];
    const float* Wc2 = (const float*)d_in[7];
    const float* bc2 = (const float*)d_in[8];
    const float* Wo  = (const float*)d_in[9];
    const float* bo  = (const float*)d_in[10];
    float* out = (float*)d_out;

    char* w = (char*)d_ws;
    auto alloc = [&](size_t bytes) {
        char* p = w;
        w += (bytes + 511) & ~(size_t)511;
        return p;
    };
    float* deg      = (float*)alloc((size_t)NN * 4);       // becomes dinv in-place
    int*   cnt      = (int*)  alloc((size_t)NN * 4);
    int*   off      = (int*)  alloc((size_t)(NN + 1) * 4);
    int*   cur      = (int*)  alloc((size_t)NN * 4);
    int*   csr_row  = (int*)  alloc((size_t)NE * 4);
    float* csr_norm = (float*)alloc((size_t)NE * 4);
    float* bufA     = (float*)alloc((size_t)NN * HD * 4);
    float* bufB     = (float*)alloc((size_t)NN * HD * 4);

    k_init <<<(NN + 255) / 256, 256, 0, stream>>>(deg, cnt, cur);
    k_count<<<(NE + 255) / 256, 256, 0, stream>>>(ei, ew, deg, cnt);
    k_dinv <<<(NN + 255) / 256, 256, 0, stream>>>(deg);
    k_scan <<<1, 1024, 0, stream>>>(cnt, off);
    k_fill <<<(NE + 255) / 256, 256, 0, stream>>>(ei, ew, deg, off, cur, csr_row, csr_norm);

    k_lin1 <<<1024, 256, 0, stream>>>(x, Wf, bf, bufA);
    k_mm64 <<<1024, 256, 0, stream>>>(bufA, Wc1, bufB);
    k_agg  <<<NN / 4, 256, 0, stream>>>(bufB, off, csr_row, csr_norm, deg, bc1, bufA);
    k_mm64 <<<1024, 256, 0, stream>>>(bufA, Wc2, bufB);
    k_agg  <<<NN / 4, 256, 0, stream>>>(bufB, off, csr_row, csr_norm, deg, bc2, bufA);
    k_out  <<<NN / 4, 256, 0, stream>>>(bufA, Wo, bo, out);
}

// Round 2
// 592.668 us; speedup vs baseline: 1.3330x; 1.3330x over previous
//
#include <hip/hip_runtime.h>
#include <cstdint>
#include <cstddef>

#define NN 100000
#define NE 1600000
#define FIN 128
#define HD 64
#define NC 40

#define SCAN_CHUNK 2048                      // elems per scan block (256 thr * 8)
#define NB_SCAN ((NN + SCAN_CHUNK - 1) / SCAN_CHUNK)   // 49

// ---------------- setup kernels ----------------

__global__ void k_init(float* deg, int* cnt, int* cur) {
    int i = blockIdx.x * 256 + threadIdx.x;
    if (i < NN) { deg[i] = 1.0f; cnt[i] = 0; cur[i] = 0; }
}

__global__ void k_count(const int* __restrict__ ei, const float* __restrict__ ew,
                        float* deg, int* cnt) {
    int e = blockIdx.x * 256 + threadIdx.x;
    if (e < NE) {
        int c = ei[NE + e];
        atomicAdd(&deg[c], ew[e]);
        atomicAdd(&cnt[c], 1);
    }
}

__global__ void k_dinv(float* deg) {
    int i = blockIdx.x * 256 + threadIdx.x;
    if (i < NN) {
        float d = deg[i];          // deg >= 1 always (self-loop weight 1)
        deg[i] = rsqrtf(d);
    }
}

// ---- two-level exclusive scan over cnt[NN] -> off[NN] (+ off[NN]=total) ----

// stage 1: per-block (2048 elems) exclusive scan into off; block total -> bsum
__launch_bounds__(256)
__global__ void k_scan_local(const int* __restrict__ cnt, int* __restrict__ off,
                             int* __restrict__ bsum) {
    __shared__ int wtot[4];
    int tid = threadIdx.x, lane = tid & 63, wid = tid >> 6;
    int base = blockIdx.x * SCAN_CHUNK + tid * 8;
    int v[8];
    int s = 0;
    if (base + 7 < NN) {
        int4 a = ((const int4*)(cnt + base))[0];
        int4 b = ((const int4*)(cnt + base))[1];
        v[0]=a.x; v[1]=a.y; v[2]=a.z; v[3]=a.w;
        v[4]=b.x; v[5]=b.y; v[6]=b.z; v[7]=b.w;
    } else {
        #pragma unroll
        for (int i = 0; i < 8; i++) v[i] = (base + i < NN) ? cnt[base + i] : 0;
    }
    #pragma unroll
    for (int i = 0; i < 8; i++) s += v[i];
    // wave inclusive scan of per-thread sums
    int inc = s;
    #pragma unroll
    for (int d = 1; d < 64; d <<= 1) {
        int t = __shfl_up(inc, d);
        if (lane >= d) inc += t;
    }
    if (lane == 63) wtot[wid] = inc;
    __syncthreads();
    int wof = 0;
    #pragma unroll
    for (int k = 0; k < 4; k++) if (k < wid) wof += wtot[k];
    int run = wof + inc - s;                // exclusive prefix of this thread
    #pragma unroll
    for (int i = 0; i < 8; i++) {
        if (base + i < NN) off[base + i] = run;
        run += v[i];
    }
    if (tid == 255) bsum[blockIdx.x] = wof + inc;   // block total
}

// stage 2: one wave scans NB_SCAN block totals (exclusive, in place); total -> off[NN]
__global__ void k_scan_bsum(int* __restrict__ bsum, int* __restrict__ off) {
    int lane = threadIdx.x;                 // 64 threads, NB_SCAN=49 < 64
    int v = (lane < NB_SCAN) ? bsum[lane] : 0;
    int inc = v;
    #pragma unroll
    for (int d = 1; d < 64; d <<= 1) {
        int t = __shfl_up(inc, d);
        if (lane >= d) inc += t;
    }
    if (lane < NB_SCAN) bsum[lane] = inc - v;
    if (lane == 63) off[NN] = inc;          // grand total
}

// stage 3: add block carries
__launch_bounds__(256)
__global__ void k_scan_add(int* __restrict__ off, const int* __restrict__ bsum) {
    int carry = bsum[blockIdx.x];
    int base = blockIdx.x * SCAN_CHUNK + threadIdx.x * 8;
    if (base + 7 < NN) {
        int4* p = (int4*)(off + base);
        int4 a = p[0], b = p[1];
        a.x+=carry; a.y+=carry; a.z+=carry; a.w+=carry;
        b.x+=carry; b.y+=carry; b.z+=carry; b.w+=carry;
        p[0] = a; p[1] = b;
    } else {
        for (int i = 0; i < 8 && base + i < NN; i++) off[base + i] += carry;
    }
}

__global__ void k_fill(const int* __restrict__ ei, const float* __restrict__ ew,
                       const float* __restrict__ dinv, const int* __restrict__ off,
                       int* cur, int* __restrict__ csr_row, float* __restrict__ csr_norm) {
    int e = blockIdx.x * 256 + threadIdx.x;
    if (e < NE) {
        int r = ei[e], c = ei[NE + e];
        float nv = dinv[r] * ew[e] * dinv[c];
        int pos = atomicAdd(&cur[c], 1);
        int slot = off[c] + pos;
        csr_row[slot] = r;
        csr_norm[slot] = nv;
    }
}

// ---------------- dense layers ----------------

// h = relu(x @ W + b): [NN,128] @ [128,64]; W column held in registers per lane
__launch_bounds__(256)
__global__ void k_lin1(const float* __restrict__ x, const float* __restrict__ W,
                       const float* __restrict__ b, float* __restrict__ out) {
    __shared__ __align__(16) float xs[4 * FIN];     // 4 node rows
    int lane = threadIdx.x & 63;
    int sub  = threadIdx.x >> 6;
    float wrs[FIN];
    #pragma unroll
    for (int k = 0; k < FIN; k++) wrs[k] = W[k * HD + lane];
    float bias = b[lane];
    const int nchunk = NN / 4;
    for (int chunk = blockIdx.x; chunk < nchunk; chunk += gridDim.x) {
        int node0 = chunk * 4;
        __syncthreads();
        if (threadIdx.x < 128)
            ((float4*)xs)[threadIdx.x] =
                ((const float4*)(x + (size_t)node0 * FIN))[threadIdx.x];
        __syncthreads();
        float acc = bias;
        const float4* xv4 = (const float4*)(xs + sub * FIN);
        #pragma unroll
        for (int k = 0; k < FIN / 4; k++) {
            float4 xv = xv4[k];
            acc += xv.x * wrs[4*k] + xv.y * wrs[4*k+1] + xv.z * wrs[4*k+2] + xv.w * wrs[4*k+3];
        }
        out[(size_t)(node0 + sub) * HD + lane] = fmaxf(acc, 0.f);
    }
}

// out = A @ W (no bias): [NN,64] @ [64,64]
__launch_bounds__(256)
__global__ void k_mm64(const float* __restrict__ A, const float* __restrict__ W,
                       float* __restrict__ out) {
    __shared__ __align__(16) float xs[4 * HD];
    int lane = threadIdx.x & 63;
    int sub  = threadIdx.x >> 6;
    float wrs[HD];
    #pragma unroll
    for (int k = 0; k < HD; k++) wrs[k] = W[k * HD + lane];
    const int nchunk = NN / 4;
    for (int chunk = blockIdx.x; chunk < nchunk; chunk += gridDim.x) {
        int node0 = chunk * 4;
        __syncthreads();
        if (threadIdx.x < 64)
            ((float4*)xs)[threadIdx.x] =
                ((const float4*)(A + (size_t)node0 * HD))[threadIdx.x];
        __syncthreads();
        float acc = 0.f;
        const float4* xv4 = (const float4*)(xs + sub * HD);
        #pragma unroll
        for (int k = 0; k < HD / 4; k++) {
            float4 xv = xv4[k];
            acc += xv.x * wrs[4*k] + xv.y * wrs[4*k+1] + xv.z * wrs[4*k+2] + xv.w * wrs[4*k+3];
        }
        out[(size_t)(node0 + sub) * HD + lane] = acc;
    }
}

// out = relu(Ahat @ Bm + bias): one wave per node, lane = feature
__global__ void k_agg(const float* __restrict__ Bm, const int* __restrict__ off,
                      const int* __restrict__ csr_row, const float* __restrict__ csr_norm,
                      const float* __restrict__ dinv, const float* __restrict__ bias,
                      float* __restrict__ outp) {
    int node = blockIdx.x * 4 + (threadIdx.x >> 6);
    int lane = threadIdx.x & 63;
    if (node >= NN) return;
    int s = off[node], e = off[node + 1];
    float di = dinv[node];
    float acc = di * di * Bm[(size_t)node * HD + lane];   // self-loop term
    int j = s;
    for (; j + 1 < e; j += 2) {
        int   r0 = csr_row[j],  r1 = csr_row[j + 1];
        float n0 = csr_norm[j], n1 = csr_norm[j + 1];
        acc += n0 * Bm[(size_t)r0 * HD + lane] + n1 * Bm[(size_t)r1 * HD + lane];
    }
    if (j < e) acc += csr_norm[j] * Bm[(size_t)csr_row[j] * HD + lane];
    outp[(size_t)node * HD + lane] = fmaxf(acc + bias[lane], 0.f);
}

// logits = H @ Wo + bo ; out = log_softmax(logits)
__launch_bounds__(256)
__global__ void k_out(const float* __restrict__ Hm, const float* __restrict__ W,
                      const float* __restrict__ b, float* __restrict__ outp) {
    __shared__ float Wl[HD * NC];
    __shared__ __align__(16) float hs[4 * HD];
    int lane = threadIdx.x & 63;
    int sub  = threadIdx.x >> 6;
    for (int i = threadIdx.x; i < HD * NC; i += 256) Wl[i] = W[i];
    int node0 = blockIdx.x * 4;
    if (threadIdx.x < 64)
        ((float4*)hs)[threadIdx.x] =
            ((const float4*)(Hm + (size_t)node0 * HD))[threadIdx.x];
    __syncthreads();
    float logit = -1e30f;
    if (lane < NC) {
        float acc = b[lane];
        #pragma unroll
        for (int k = 0; k < HD; k++) acc += hs[sub * HD + k] * Wl[k * NC + lane];
        logit = acc;
    }
    float m = logit;
    #pragma unroll
    for (int s = 32; s > 0; s >>= 1) m = fmaxf(m, __shfl_xor(m, s));
    float ex = (lane < NC) ? expf(logit - m) : 0.f;
    float sum = ex;
    #pragma unroll
    for (int s = 32; s > 0; s >>= 1) sum += __shfl_xor(sum, s);
    if (lane < NC) outp[(size_t)node0 * NC + sub * NC + lane] = (logit - m) - logf(sum);
}

// ---------------- launch ----------------

extern "C" void kernel_launch(void* const* d_in, const int* in_sizes, int n_in,
                              void* d_out, int out_size, void* d_ws, size_t ws_size,
                              hipStream_t stream) {
    const float* x   = (const float*)d_in[0];
    const int*   ei  = (const int*)  d_in[1];
    const float* ew  = (const float*)d_in[2];
    const float* Wf  = (const float*)d_in[3];
    const float* bf  = (const float*)d_in[4];
    const float* Wc1 = (const float*)d_in[5];
    const float* bc1 = (const float*)d_in[6];
    const float* Wc2 = (const float*)d_in[7];
    const float* bc2 = (const float*)d_in[8];
    const float* Wo  = (const float*)d_in[9];
    const float* bo  = (const float*)d_in[10];
    float* out = (float*)d_out;

    char* w = (char*)d_ws;
    auto alloc = [&](size_t bytes) {
        char* p = w;
        w += (bytes + 511) & ~(size_t)511;
        return p;
    };
    float* deg      = (float*)alloc((size_t)NN * 4);       // becomes dinv in-place
    int*   cnt      = (int*)  alloc((size_t)NN * 4);
    int*   off      = (int*)  alloc((size_t)(NN + 1) * 4);
    int*   cur      = (int*)  alloc((size_t)NN * 4);
    int*   bsum     = (int*)  alloc((size_t)NB_SCAN * 4);
    int*   csr_row  = (int*)  alloc((size_t)NE * 4);
    float* csr_norm = (float*)alloc((size_t)NE * 4);
    float* bufA     = (float*)alloc((size_t)NN * HD * 4);
    float* bufB     = (float*)alloc((size_t)NN * HD * 4);

    k_init      <<<(NN + 255) / 256, 256, 0, stream>>>(deg, cnt, cur);
    k_count     <<<(NE + 255) / 256, 256, 0, stream>>>(ei, ew, deg, cnt);
    k_dinv      <<<(NN + 255) / 256, 256, 0, stream>>>(deg);
    k_scan_local<<<NB_SCAN, 256, 0, stream>>>(cnt, off, bsum);
    k_scan_bsum <<<1, 64, 0, stream>>>(bsum, off);
    k_scan_add  <<<NB_SCAN, 256, 0, stream>>>(off, bsum);
    k_fill      <<<(NE + 255) / 256, 256, 0, stream>>>(ei, ew, deg, off, cur, csr_row, csr_norm);

    k_lin1 <<<1024, 256, 0, stream>>>(x, Wf, bf, bufA);
    k_mm64 <<<1024, 256, 0, stream>>>(bufA, Wc1, bufB);
    k_agg  <<<NN / 4, 256, 0, stream>>>(bufB, off, csr_row, csr_norm, deg, bc1, bufA);
    k_mm64 <<<1024, 256, 0, stream>>>(bufA, Wc2, bufB);
    k_agg  <<<NN / 4, 256, 0, stream>>>(bufB, off, csr_row, csr_norm, deg, bc2, bufA);
    k_out  <<<NN / 4, 256, 0, stream>>>(bufA, Wo, bo, out);
}

// Round 3
// 437.598 us; speedup vs baseline: 1.8054x; 1.3544x over previous
//
#include <hip/hip_runtime.h>
#include <cstdint>
#include <cstddef>

#define NN 100000
#define NE 1600000
#define FIN 128
#define HD 64
#define NC 40

#define SCAN_CHUNK 2048                      // elems per scan block (256 thr * 8)
#define NB_SCAN ((NN + SCAN_CHUNK - 1) / SCAN_CHUNK)   // 49

typedef unsigned long long ull;

// ---------------- setup kernels ----------------

__global__ void k_init(ull* packed) {
    int i = blockIdx.x * 256 + threadIdx.x;
    if (i < NN) packed[i] = 0ull;
}

// one packed 64-bit atomic per edge: hi32 = count, lo32 = Q8.24 weight sum.
// returned old hi32 = this edge's slot position within its target node.
__global__ void k_count(const int* __restrict__ ei, const float* __restrict__ ew,
                        ull* __restrict__ packed, unsigned short* __restrict__ pos) {
    int e = blockIdx.x * 256 + threadIdx.x;
    if (e < NE) {
        int c = ei[NE + e];
        unsigned int fx = __float2uint_rn(ew[e] * 16777216.0f);   // Q8.24
        ull old = atomicAdd(&packed[c], (1ull << 32) | (ull)fx);
        pos[e] = (unsigned short)(old >> 32);
    }
}

__global__ void k_dinv(const ull* __restrict__ packed, float* __restrict__ dinv,
                       int* __restrict__ cnt) {
    int i = blockIdx.x * 256 + threadIdx.x;
    if (i < NN) {
        ull p = packed[i];
        cnt[i] = (int)(p >> 32);
        float deg = 1.0f + (float)(unsigned int)(p & 0xFFFFFFFFull) * (1.0f / 16777216.0f);
        dinv[i] = rsqrtf(deg);
    }
}

// ---- two-level exclusive scan over cnt[NN] -> off[NN] (+ off[NN]=total) ----

__launch_bounds__(256)
__global__ void k_scan_local(const int* __restrict__ cnt, int* __restrict__ off,
                             int* __restrict__ bsum) {
    __shared__ int wtot[4];
    int tid = threadIdx.x, lane = tid & 63, wid = tid >> 6;
    int base = blockIdx.x * SCAN_CHUNK + tid * 8;
    int v[8];
    int s = 0;
    if (base + 7 < NN) {
        int4 a = ((const int4*)(cnt + base))[0];
        int4 b = ((const int4*)(cnt + base))[1];
        v[0]=a.x; v[1]=a.y; v[2]=a.z; v[3]=a.w;
        v[4]=b.x; v[5]=b.y; v[6]=b.z; v[7]=b.w;
    } else {
        #pragma unroll
        for (int i = 0; i < 8; i++) v[i] = (base + i < NN) ? cnt[base + i] : 0;
    }
    #pragma unroll
    for (int i = 0; i < 8; i++) s += v[i];
    int inc = s;
    #pragma unroll
    for (int d = 1; d < 64; d <<= 1) {
        int t = __shfl_up(inc, d);
        if (lane >= d) inc += t;
    }
    if (lane == 63) wtot[wid] = inc;
    __syncthreads();
    int wof = 0;
    #pragma unroll
    for (int k = 0; k < 4; k++) if (k < wid) wof += wtot[k];
    int run = wof + inc - s;                // exclusive prefix of this thread
    #pragma unroll
    for (int i = 0; i < 8; i++) {
        if (base + i < NN) off[base + i] = run;
        run += v[i];
    }
    if (tid == 255) bsum[blockIdx.x] = wof + inc;   // block total
}

__global__ void k_scan_bsum(int* __restrict__ bsum, int* __restrict__ off) {
    int lane = threadIdx.x;                 // 64 threads, NB_SCAN=49 < 64
    int v = (lane < NB_SCAN) ? bsum[lane] : 0;
    int inc = v;
    #pragma unroll
    for (int d = 1; d < 64; d <<= 1) {
        int t = __shfl_up(inc, d);
        if (lane >= d) inc += t;
    }
    if (lane < NB_SCAN) bsum[lane] = inc - v;
    if (lane == 63) off[NN] = inc;          // grand total
}

__launch_bounds__(256)
__global__ void k_scan_add(int* __restrict__ off, const int* __restrict__ bsum) {
    int carry = bsum[blockIdx.x];
    int base = blockIdx.x * SCAN_CHUNK + threadIdx.x * 8;
    if (base + 7 < NN) {
        int4* p = (int4*)(off + base);
        int4 a = p[0], b = p[1];
        a.x+=carry; a.y+=carry; a.z+=carry; a.w+=carry;
        b.x+=carry; b.y+=carry; b.z+=carry; b.w+=carry;
        p[0] = a; p[1] = b;
    } else {
        for (int i = 0; i < 8 && base + i < NN; i++) off[base + i] += carry;
    }
}

// atomic-free fill: slot = off[col] + pos[e]; one fused 8B store
__global__ void k_fill(const int* __restrict__ ei, const float* __restrict__ ew,
                       const float* __restrict__ dinv, const int* __restrict__ off,
                       const unsigned short* __restrict__ pos, uint2* __restrict__ csr) {
    int e = blockIdx.x * 256 + threadIdx.x;
    if (e < NE) {
        int r = ei[e], c = ei[NE + e];
        float nv = dinv[r] * ew[e] * dinv[c];
        int slot = off[c] + (int)pos[e];
        csr[slot] = make_uint2((unsigned)r, __float_as_uint(nv));
    }
}

// ---------------- dense layers ----------------

__launch_bounds__(256)
__global__ void k_lin1(const float* __restrict__ x, const float* __restrict__ W,
                       const float* __restrict__ b, float* __restrict__ out) {
    __shared__ __align__(16) float xs[4 * FIN];     // 4 node rows
    int lane = threadIdx.x & 63;
    int sub  = threadIdx.x >> 6;
    float wrs[FIN];
    #pragma unroll
    for (int k = 0; k < FIN; k++) wrs[k] = W[k * HD + lane];
    float bias = b[lane];
    const int nchunk = NN / 4;
    for (int chunk = blockIdx.x; chunk < nchunk; chunk += gridDim.x) {
        int node0 = chunk * 4;
        __syncthreads();
        if (threadIdx.x < 128)
            ((float4*)xs)[threadIdx.x] =
                ((const float4*)(x + (size_t)node0 * FIN))[threadIdx.x];
        __syncthreads();
        float acc = bias;
        const float4* xv4 = (const float4*)(xs + sub * FIN);
        #pragma unroll
        for (int k = 0; k < FIN / 4; k++) {
            float4 xv = xv4[k];
            acc += xv.x * wrs[4*k] + xv.y * wrs[4*k+1] + xv.z * wrs[4*k+2] + xv.w * wrs[4*k+3];
        }
        out[(size_t)(node0 + sub) * HD + lane] = fmaxf(acc, 0.f);
    }
}

__launch_bounds__(256)
__global__ void k_mm64(const float* __restrict__ A, const float* __restrict__ W,
                       float* __restrict__ out) {
    __shared__ __align__(16) float xs[4 * HD];
    int lane = threadIdx.x & 63;
    int sub  = threadIdx.x >> 6;
    float wrs[HD];
    #pragma unroll
    for (int k = 0; k < HD; k++) wrs[k] = W[k * HD + lane];
    const int nchunk = NN / 4;
    for (int chunk = blockIdx.x; chunk < nchunk; chunk += gridDim.x) {
        int node0 = chunk * 4;
        __syncthreads();
        if (threadIdx.x < 64)
            ((float4*)xs)[threadIdx.x] =
                ((const float4*)(A + (size_t)node0 * HD))[threadIdx.x];
        __syncthreads();
        float acc = 0.f;
        const float4* xv4 = (const float4*)(xs + sub * HD);
        #pragma unroll
        for (int k = 0; k < HD / 4; k++) {
            float4 xv = xv4[k];
            acc += xv.x * wrs[4*k] + xv.y * wrs[4*k+1] + xv.z * wrs[4*k+2] + xv.w * wrs[4*k+3];
        }
        out[(size_t)(node0 + sub) * HD + lane] = acc;
    }
}

// out = relu(Ahat @ Bm + bias): one wave per node, lane = feature
__global__ void k_agg(const float* __restrict__ Bm, const int* __restrict__ off,
                      const uint2* __restrict__ csr, const float* __restrict__ dinv,
                      const float* __restrict__ bias, float* __restrict__ outp) {
    int node = blockIdx.x * 4 + (threadIdx.x >> 6);
    int lane = threadIdx.x & 63;
    if (node >= NN) return;
    int s = off[node], e = off[node + 1];
    float di = dinv[node];
    float acc0 = di * di * Bm[(size_t)node * HD + lane];   // self-loop term
    float acc1 = 0.f;
    int j = s;
    for (; j + 3 < e; j += 4) {
        uint2 c0 = csr[j], c1 = csr[j+1], c2 = csr[j+2], c3 = csr[j+3];
        acc0 += __uint_as_float(c0.y) * Bm[(size_t)c0.x * HD + lane]
              + __uint_as_float(c1.y) * Bm[(size_t)c1.x * HD + lane];
        acc1 += __uint_as_float(c2.y) * Bm[(size_t)c2.x * HD + lane]
              + __uint_as_float(c3.y) * Bm[(size_t)c3.x * HD + lane];
    }
    for (; j < e; j++) {
        uint2 c0 = csr[j];
        acc0 += __uint_as_float(c0.y) * Bm[(size_t)c0.x * HD + lane];
    }
    outp[(size_t)node * HD + lane] = fmaxf(acc0 + acc1 + bias[lane], 0.f);
}

// logits = H @ Wo + bo ; out = log_softmax(logits)
__launch_bounds__(256)
__global__ void k_out(const float* __restrict__ Hm, const float* __restrict__ W,
                      const float* __restrict__ b, float* __restrict__ outp) {
    __shared__ float Wl[HD * NC];
    __shared__ __align__(16) float hs[4 * HD];
    int lane = threadIdx.x & 63;
    int sub  = threadIdx.x >> 6;
    for (int i = threadIdx.x; i < HD * NC; i += 256) Wl[i] = W[i];
    int node0 = blockIdx.x * 4;
    if (threadIdx.x < 64)
        ((float4*)hs)[threadIdx.x] =
            ((const float4*)(Hm + (size_t)node0 * HD))[threadIdx.x];
    __syncthreads();
    float logit = -1e30f;
    if (lane < NC) {
        float acc = b[lane];
        #pragma unroll
        for (int k = 0; k < HD; k++) acc += hs[sub * HD + k] * Wl[k * NC + lane];
        logit = acc;
    }
    float m = logit;
    #pragma unroll
    for (int s = 32; s > 0; s >>= 1) m = fmaxf(m, __shfl_xor(m, s));
    float ex = (lane < NC) ? expf(logit - m) : 0.f;
    float sum = ex;
    #pragma unroll
    for (int s = 32; s > 0; s >>= 1) sum += __shfl_xor(sum, s);
    if (lane < NC) outp[(size_t)node0 * NC + sub * NC + lane] = (logit - m) - logf(sum);
}

// ---------------- launch ----------------

extern "C" void kernel_launch(void* const* d_in, const int* in_sizes, int n_in,
                              void* d_out, int out_size, void* d_ws, size_t ws_size,
                              hipStream_t stream) {
    const float* x   = (const float*)d_in[0];
    const int*   ei  = (const int*)  d_in[1];
    const float* ew  = (const float*)d_in[2];
    const float* Wf  = (const float*)d_in[3];
    const float* bf  = (const float*)d_in[4];
    const float* Wc1 = (const float*)d_in[5];
    const float* bc1 = (const float*)d_in[6];
    const float* Wc2 = (const float*)d_in[7];
    const float* bc2 = (const float*)d_in[8];
    const float* Wo  = (const float*)d_in[9];
    const float* bo  = (const float*)d_in[10];
    float* out = (float*)d_out;

    char* w = (char*)d_ws;
    auto alloc = [&](size_t bytes) {
        char* p = w;
        w += (bytes + 511) & ~(size_t)511;
        return p;
    };
    float* dinv = (float*)alloc((size_t)NN * 4);
    int*   off  = (int*)  alloc((size_t)(NN + 1) * 4);
    int*   bsum = (int*)  alloc((size_t)NB_SCAN * 4);
    uint2* csr  = (uint2*)alloc((size_t)NE * 8);
    float* bufA = (float*)alloc((size_t)NN * HD * 4);
    float* bufB = (float*)alloc((size_t)NN * HD * 4);
    // overlays: dead before their hosts' first use (stream-ordered)
    unsigned short* pos = (unsigned short*)bufA;          // dead after k_fill; bufA first written by k_lin1
    ull* packed = (ull*)bufB;                             // dead after k_dinv; bufB first written by k_mm64
    int* cnt    = (int*)((char*)bufB + (size_t)NN * 8);   // dead after scan

    k_init      <<<(NN + 255) / 256, 256, 0, stream>>>(packed);
    k_count     <<<(NE + 255) / 256, 256, 0, stream>>>(ei, ew, packed, pos);
    k_dinv      <<<(NN + 255) / 256, 256, 0, stream>>>(packed, dinv, cnt);
    k_scan_local<<<NB_SCAN, 256, 0, stream>>>(cnt, off, bsum);
    k_scan_bsum <<<1, 64, 0, stream>>>(bsum, off);
    k_scan_add  <<<NB_SCAN, 256, 0, stream>>>(off, bsum);
    k_fill      <<<(NE + 255) / 256, 256, 0, stream>>>(ei, ew, dinv, off, pos, csr);

    k_lin1 <<<1024, 256, 0, stream>>>(x, Wf, bf, bufA);
    k_mm64 <<<1024, 256, 0, stream>>>(bufA, Wc1, bufB);
    k_agg  <<<NN / 4, 256, 0, stream>>>(bufB, off, csr, dinv, bc1, bufA);
    k_mm64 <<<1024, 256, 0, stream>>>(bufA, Wc2, bufB);
    k_agg  <<<NN / 4, 256, 0, stream>>>(bufB, off, csr, dinv, bc2, bufA);
    k_out  <<<NN / 4, 256, 0, stream>>>(bufA, Wo, bo, out);
}

// Round 4
// 437.286 us; speedup vs baseline: 1.8067x; 1.0007x over previous
//
#include <hip/hip_runtime.h>
#include <hip/hip_bf16.h>
#include <cstdint>
#include <cstddef>

#define NN 100000
#define NE 1600000
#define FIN 128
#define HD 64
#define NC 40

#define SCAN_CHUNK 2048                      // elems per scan block (256 thr * 8)
#define NB_SCAN ((NN + SCAN_CHUNK - 1) / SCAN_CHUNK)   // 49

typedef unsigned long long ull;
typedef unsigned short u16;
typedef unsigned int u32;

__device__ __forceinline__ float b2f(u16 u) {
    return __uint_as_float(((u32)u) << 16);
}

// ---------------- setup kernels ----------------

// one packed 64-bit atomic per edge: hi32 = count, lo32 = Q8.24 weight sum.
// returned old hi32 = this edge's slot position within its target node.
__global__ void k_count(const int* __restrict__ ei, const float* __restrict__ ew,
                        ull* __restrict__ packed, u16* __restrict__ pos) {
    int e = blockIdx.x * 256 + threadIdx.x;
    if (e < NE) {
        int c = ei[NE + e];
        u32 fx = __float2uint_rn(ew[e] * 16777216.0f);   // Q8.24
        ull old = atomicAdd(&packed[c], (1ull << 32) | (ull)fx);
        pos[e] = (u16)(old >> 32);
    }
}

// ---- two-level exclusive scan over counts (in packed hi32) -> off; also emits dinv ----

__launch_bounds__(256)
__global__ void k_scan_local(const ull* __restrict__ packed, int* __restrict__ off,
                             int* __restrict__ bsum, float* __restrict__ dinv) {
    __shared__ int wtot[4];
    int tid = threadIdx.x, lane = tid & 63, wid = tid >> 6;
    int base = blockIdx.x * SCAN_CHUNK + tid * 8;
    int v[8];
    int s = 0;
    #pragma unroll
    for (int i = 0; i < 8; i++) {
        if (base + i < NN) {
            ull p = packed[base + i];
            v[i] = (int)(p >> 32);
            float deg = 1.0f + (float)(u32)(p & 0xFFFFFFFFull) * (1.0f / 16777216.0f);
            dinv[base + i] = rsqrtf(deg);
        } else v[i] = 0;
    }
    #pragma unroll
    for (int i = 0; i < 8; i++) s += v[i];
    int inc = s;
    #pragma unroll
    for (int d = 1; d < 64; d <<= 1) {
        int t = __shfl_up(inc, d);
        if (lane >= d) inc += t;
    }
    if (lane == 63) wtot[wid] = inc;
    __syncthreads();
    int wof = 0;
    #pragma unroll
    for (int k = 0; k < 4; k++) if (k < wid) wof += wtot[k];
    int run = wof + inc - s;                // exclusive prefix of this thread
    #pragma unroll
    for (int i = 0; i < 8; i++) {
        if (base + i < NN) off[base + i] = run;
        run += v[i];
    }
    if (tid == 255) bsum[blockIdx.x] = wof + inc;   // block total
}

__global__ void k_scan_bsum(int* __restrict__ bsum, int* __restrict__ off) {
    int lane = threadIdx.x;                 // 64 threads, NB_SCAN=49 < 64
    int v = (lane < NB_SCAN) ? bsum[lane] : 0;
    int inc = v;
    #pragma unroll
    for (int d = 1; d < 64; d <<= 1) {
        int t = __shfl_up(inc, d);
        if (lane >= d) inc += t;
    }
    if (lane < NB_SCAN) bsum[lane] = inc - v;
    if (lane == 63) off[NN] = inc;          // grand total
}

__launch_bounds__(256)
__global__ void k_scan_add(int* __restrict__ off, const int* __restrict__ bsum) {
    int carry = bsum[blockIdx.x];
    int base = blockIdx.x * SCAN_CHUNK + threadIdx.x * 8;
    if (base + 7 < NN) {
        int4* p = (int4*)(off + base);
        int4 a = p[0], b = p[1];
        a.x+=carry; a.y+=carry; a.z+=carry; a.w+=carry;
        b.x+=carry; b.y+=carry; b.z+=carry; b.w+=carry;
        p[0] = a; p[1] = b;
    } else {
        for (int i = 0; i < 8 && base + i < NN; i++) off[base + i] += carry;
    }
}

// atomic-free fill: slot = off[col] + pos[e]; one fused 8B store
__global__ void k_fill(const int* __restrict__ ei, const float* __restrict__ ew,
                       const float* __restrict__ dinv, const int* __restrict__ off,
                       const u16* __restrict__ pos, uint2* __restrict__ csr) {
    int e = blockIdx.x * 256 + threadIdx.x;
    if (e < NE) {
        int r = ei[e], c = ei[NE + e];
        float nv = dinv[r] * ew[e] * dinv[c];
        int slot = off[c] + (int)pos[e];
        csr[slot] = make_uint2((u32)r, __float_as_uint(nv));
    }
}

// ---------------- dense layers ----------------

__launch_bounds__(256)
__global__ void k_lin1(const float* __restrict__ x, const float* __restrict__ W,
                       const float* __restrict__ b, float* __restrict__ out) {
    __shared__ __align__(16) float xs[4 * FIN];     // 4 node rows
    int lane = threadIdx.x & 63;
    int sub  = threadIdx.x >> 6;
    float wrs[FIN];
    #pragma unroll
    for (int k = 0; k < FIN; k++) wrs[k] = W[k * HD + lane];
    float bias = b[lane];
    const int nchunk = NN / 4;
    for (int chunk = blockIdx.x; chunk < nchunk; chunk += gridDim.x) {
        int node0 = chunk * 4;
        __syncthreads();
        if (threadIdx.x < 128)
            ((float4*)xs)[threadIdx.x] =
                ((const float4*)(x + (size_t)node0 * FIN))[threadIdx.x];
        __syncthreads();
        float acc = bias;
        const float4* xv4 = (const float4*)(xs + sub * FIN);
        #pragma unroll
        for (int k = 0; k < FIN / 4; k++) {
            float4 xv = xv4[k];
            acc += xv.x * wrs[4*k] + xv.y * wrs[4*k+1] + xv.z * wrs[4*k+2] + xv.w * wrs[4*k+3];
        }
        out[(size_t)(node0 + sub) * HD + lane] = fmaxf(acc, 0.f);
    }
}

// out(bf16) = A @ W (no bias): [NN,64] @ [64,64]; f32 accumulate, bf16 store
__launch_bounds__(256)
__global__ void k_mm64(const float* __restrict__ A, const float* __restrict__ W,
                       __hip_bfloat16* __restrict__ out) {
    __shared__ __align__(16) float xs[4 * HD];
    int lane = threadIdx.x & 63;
    int sub  = threadIdx.x >> 6;
    float wrs[HD];
    #pragma unroll
    for (int k = 0; k < HD; k++) wrs[k] = W[k * HD + lane];
    const int nchunk = NN / 4;
    for (int chunk = blockIdx.x; chunk < nchunk; chunk += gridDim.x) {
        int node0 = chunk * 4;
        __syncthreads();
        if (threadIdx.x < 64)
            ((float4*)xs)[threadIdx.x] =
                ((const float4*)(A + (size_t)node0 * HD))[threadIdx.x];
        __syncthreads();
        float acc = 0.f;
        const float4* xv4 = (const float4*)(xs + sub * HD);
        #pragma unroll
        for (int k = 0; k < HD / 4; k++) {
            float4 xv = xv4[k];
            acc += xv.x * wrs[4*k] + xv.y * wrs[4*k+1] + xv.z * wrs[4*k+2] + xv.w * wrs[4*k+3];
        }
        out[(size_t)(node0 + sub) * HD + lane] = __float2bfloat16(acc);
    }
}

// out = relu(Ahat @ Bm + bias): one wave per node, lane = feature; bf16 gather table
__global__ void k_agg(const u16* __restrict__ Bm, const int* __restrict__ off,
                      const uint2* __restrict__ csr, const float* __restrict__ dinv,
                      const float* __restrict__ bias, float* __restrict__ outp) {
    int node = blockIdx.x * 4 + (threadIdx.x >> 6);
    int lane = threadIdx.x & 63;
    if (node >= NN) return;
    int s = off[node], e = off[node + 1];
    float di = dinv[node];
    float acc0 = di * di * b2f(Bm[(size_t)node * HD + lane]);   // self-loop term
    float acc1 = 0.f, acc2 = 0.f, acc3 = 0.f;
    for (int j = s; j < e; j += 8) {
        // csr allocated with +8 pad entries; over-reads are in-bounds,
        // invalid lanes get weight 0 and re-read the node's own (hot) row.
        uint2 c0 = csr[j],   c1 = csr[j+1], c2 = csr[j+2], c3 = csr[j+3];
        uint2 c4 = csr[j+4], c5 = csr[j+5], c6 = csr[j+6], c7 = csr[j+7];
        u32 r0 = (j+0 < e) ? c0.x : (u32)node;  float w0 = (j+0 < e) ? __uint_as_float(c0.y) : 0.f;
        u32 r1 = (j+1 < e) ? c1.x : (u32)node;  float w1 = (j+1 < e) ? __uint_as_float(c1.y) : 0.f;
        u32 r2 = (j+2 < e) ? c2.x : (u32)node;  float w2 = (j+2 < e) ? __uint_as_float(c2.y) : 0.f;
        u32 r3 = (j+3 < e) ? c3.x : (u32)node;  float w3 = (j+3 < e) ? __uint_as_float(c3.y) : 0.f;
        u32 r4 = (j+4 < e) ? c4.x : (u32)node;  float w4 = (j+4 < e) ? __uint_as_float(c4.y) : 0.f;
        u32 r5 = (j+5 < e) ? c5.x : (u32)node;  float w5 = (j+5 < e) ? __uint_as_float(c5.y) : 0.f;
        u32 r6 = (j+6 < e) ? c6.x : (u32)node;  float w6 = (j+6 < e) ? __uint_as_float(c6.y) : 0.f;
        u32 r7 = (j+7 < e) ? c7.x : (u32)node;  float w7 = (j+7 < e) ? __uint_as_float(c7.y) : 0.f;
        float f0 = b2f(Bm[(size_t)r0 * HD + lane]);
        float f1 = b2f(Bm[(size_t)r1 * HD + lane]);
        float f2 = b2f(Bm[(size_t)r2 * HD + lane]);
        float f3 = b2f(Bm[(size_t)r3 * HD + lane]);
        float f4 = b2f(Bm[(size_t)r4 * HD + lane]);
        float f5 = b2f(Bm[(size_t)r5 * HD + lane]);
        float f6 = b2f(Bm[(size_t)r6 * HD + lane]);
        float f7 = b2f(Bm[(size_t)r7 * HD + lane]);
        acc0 += w0 * f0 + w4 * f4;
        acc1 += w1 * f1 + w5 * f5;
        acc2 += w2 * f2 + w6 * f6;
        acc3 += w3 * f3 + w7 * f7;
    }
    outp[(size_t)node * HD + lane] = fmaxf((acc0 + acc1) + (acc2 + acc3) + bias[lane], 0.f);
}

// logits = H @ Wo + bo ; out = log_softmax(logits)
__launch_bounds__(256)
__global__ void k_out(const float* __restrict__ Hm, const float* __restrict__ W,
                      const float* __restrict__ b, float* __restrict__ outp) {
    __shared__ float Wl[HD * NC];
    __shared__ __align__(16) float hs[4 * HD];
    int lane = threadIdx.x & 63;
    int sub  = threadIdx.x >> 6;
    for (int i = threadIdx.x; i < HD * NC; i += 256) Wl[i] = W[i];
    int node0 = blockIdx.x * 4;
    if (threadIdx.x < 64)
        ((float4*)hs)[threadIdx.x] =
            ((const float4*)(Hm + (size_t)node0 * HD))[threadIdx.x];
    __syncthreads();
    float logit = -1e30f;
    if (lane < NC) {
        float acc = b[lane];
        #pragma unroll
        for (int k = 0; k < HD; k++) acc += hs[sub * HD + k] * Wl[k * NC + lane];
        logit = acc;
    }
    float m = logit;
    #pragma unroll
    for (int s = 32; s > 0; s >>= 1) m = fmaxf(m, __shfl_xor(m, s));
    float ex = (lane < NC) ? expf(logit - m) : 0.f;
    float sum = ex;
    #pragma unroll
    for (int s = 32; s > 0; s >>= 1) sum += __shfl_xor(sum, s);
    if (lane < NC) outp[(size_t)node0 * NC + sub * NC + lane] = (logit - m) - logf(sum);
}

// ---------------- launch ----------------

extern "C" void kernel_launch(void* const* d_in, const int* in_sizes, int n_in,
                              void* d_out, int out_size, void* d_ws, size_t ws_size,
                              hipStream_t stream) {
    const float* x   = (const float*)d_in[0];
    const int*   ei  = (const int*)  d_in[1];
    const float* ew  = (const float*)d_in[2];
    const float* Wf  = (const float*)d_in[3];
    const float* bf  = (const float*)d_in[4];
    const float* Wc1 = (const float*)d_in[5];
    const float* bc1 = (const float*)d_in[6];
    const float* Wc2 = (const float*)d_in[7];
    const float* bc2 = (const float*)d_in[8];
    const float* Wo  = (const float*)d_in[9];
    const float* bo  = (const float*)d_in[10];
    float* out = (float*)d_out;

    char* w = (char*)d_ws;
    auto alloc = [&](size_t bytes) {
        char* p = w;
        w += (bytes + 511) & ~(size_t)511;
        return p;
    };
    float* dinv = (float*)alloc((size_t)NN * 4);
    int*   off  = (int*)  alloc((size_t)(NN + 1) * 4);
    int*   bsum = (int*)  alloc((size_t)NB_SCAN * 4);
    uint2* csr  = (uint2*)alloc((size_t)(NE + 8) * 8);    // +8 pad for over-read
    float* bufA = (float*)alloc((size_t)NN * HD * 4);     // f32 h buffers
    char*  bufB = (char*) alloc((size_t)NN * HD * 4);     // bf16 table + overlays
    // overlays: dead before their hosts' first use (stream-ordered)
    u16* pos    = (u16*)bufA;                 // dead after k_fill; bufA first written by k_lin1
    ull* packed = (ull*)bufB;                 // dead after k_scan_local; bufB first written by k_mm64
    __hip_bfloat16* tbl = (__hip_bfloat16*)bufB;

    hipMemsetAsync(packed, 0, (size_t)NN * 8, stream);
    k_count     <<<(NE + 255) / 256, 256, 0, stream>>>(ei, ew, packed, pos);
    k_scan_local<<<NB_SCAN, 256, 0, stream>>>(packed, off, bsum, dinv);
    k_scan_bsum <<<1, 64, 0, stream>>>(bsum, off);
    k_scan_add  <<<NB_SCAN, 256, 0, stream>>>(off, bsum);
    k_fill      <<<(NE + 255) / 256, 256, 0, stream>>>(ei, ew, dinv, off, pos, csr);

    k_lin1 <<<1024, 256, 0, stream>>>(x, Wf, bf, bufA);
    k_mm64 <<<1024, 256, 0, stream>>>(bufA, Wc1, tbl);
    k_agg  <<<NN / 4, 256, 0, stream>>>((const u16*)tbl, off, csr, dinv, bc1, bufA);
    k_mm64 <<<1024, 256, 0, stream>>>(bufA, Wc2, tbl);
    k_agg  <<<NN / 4, 256, 0, stream>>>((const u16*)tbl, off, csr, dinv, bc2, bufA);
    k_out  <<<NN / 4, 256, 0, stream>>>(bufA, Wo, bo, out);
}

// Round 5
// 380.549 us; speedup vs baseline: 2.0761x; 1.1491x over previous
//
#include <hip/hip_runtime.h>
#include <hip/hip_bf16.h>
#include <cstdint>
#include <cstddef>

#define NN 100000
#define NE 1600000
#define FIN 128
#define HD 64
#define NC 40

#define SCAN_CHUNK 2048                      // elems per scan block (256 thr * 8)
#define NB_SCAN ((NN + SCAN_CHUNK - 1) / SCAN_CHUNK)   // 49

typedef unsigned long long ull;
typedef unsigned short u16;
typedef unsigned int u32;

__device__ __forceinline__ float u2lo(u32 u) { return __uint_as_float(u << 16); }
__device__ __forceinline__ float u2hi(u32 u) { return __uint_as_float(u & 0xFFFF0000u); }

// ---------------- setup kernels ----------------

// one packed 64-bit atomic per edge: hi32 = count, lo32 = Q8.24 weight sum.
// returned old hi32 = this edge's slot position within its target node.
__global__ void k_count(const int* __restrict__ ei, const float* __restrict__ ew,
                        ull* __restrict__ packed, u16* __restrict__ pos) {
    int e = blockIdx.x * 256 + threadIdx.x;
    if (e < NE) {
        int c = ei[NE + e];
        u32 fx = __float2uint_rn(ew[e] * 16777216.0f);   // Q8.24
        ull old = atomicAdd(&packed[c], (1ull << 32) | (ull)fx);
        pos[e] = (u16)(old >> 32);
    }
}

// ---- two-level exclusive scan over counts (in packed hi32) -> off; also emits dinv ----

__launch_bounds__(256)
__global__ void k_scan_local(const ull* __restrict__ packed, int* __restrict__ off,
                             int* __restrict__ bsum, float* __restrict__ dinv) {
    __shared__ int wtot[4];
    int tid = threadIdx.x, lane = tid & 63, wid = tid >> 6;
    int base = blockIdx.x * SCAN_CHUNK + tid * 8;
    int v[8];
    int s = 0;
    #pragma unroll
    for (int i = 0; i < 8; i++) {
        if (base + i < NN) {
            ull p = packed[base + i];
            v[i] = (int)(p >> 32);
            float deg = 1.0f + (float)(u32)(p & 0xFFFFFFFFull) * (1.0f / 16777216.0f);
            dinv[base + i] = rsqrtf(deg);
        } else v[i] = 0;
    }
    #pragma unroll
    for (int i = 0; i < 8; i++) s += v[i];
    int inc = s;
    #pragma unroll
    for (int d = 1; d < 64; d <<= 1) {
        int t = __shfl_up(inc, d);
        if (lane >= d) inc += t;
    }
    if (lane == 63) wtot[wid] = inc;
    __syncthreads();
    int wof = 0;
    #pragma unroll
    for (int k = 0; k < 4; k++) if (k < wid) wof += wtot[k];
    int run = wof + inc - s;                // exclusive prefix of this thread
    #pragma unroll
    for (int i = 0; i < 8; i++) {
        if (base + i < NN) off[base + i] = run;
        run += v[i];
    }
    if (tid == 255) bsum[blockIdx.x] = wof + inc;   // block total
}

__global__ void k_scan_bsum(int* __restrict__ bsum, int* __restrict__ off) {
    int lane = threadIdx.x;                 // 64 threads, NB_SCAN=49 < 64
    int v = (lane < NB_SCAN) ? bsum[lane] : 0;
    int inc = v;
    #pragma unroll
    for (int d = 1; d < 64; d <<= 1) {
        int t = __shfl_up(inc, d);
        if (lane >= d) inc += t;
    }
    if (lane < NB_SCAN) bsum[lane] = inc - v;
    if (lane == 63) off[NN] = inc;          // grand total
}

__launch_bounds__(256)
__global__ void k_scan_add(int* __restrict__ off, const int* __restrict__ bsum) {
    int carry = bsum[blockIdx.x];
    int base = blockIdx.x * SCAN_CHUNK + threadIdx.x * 8;
    if (base + 7 < NN) {
        int4* p = (int4*)(off + base);
        int4 a = p[0], b = p[1];
        a.x+=carry; a.y+=carry; a.z+=carry; a.w+=carry;
        b.x+=carry; b.y+=carry; b.z+=carry; b.w+=carry;
        p[0] = a; p[1] = b;
    } else {
        for (int i = 0; i < 8 && base + i < NN; i++) off[base + i] += carry;
    }
}

// atomic-free fill: slot = off[col] + pos[e]; one fused 8B store
__global__ void k_fill(const int* __restrict__ ei, const float* __restrict__ ew,
                       const float* __restrict__ dinv, const int* __restrict__ off,
                       const u16* __restrict__ pos, uint2* __restrict__ csr) {
    int e = blockIdx.x * 256 + threadIdx.x;
    if (e < NE) {
        int r = ei[e], c = ei[NE + e];
        float nv = dinv[r] * ew[e] * dinv[c];
        int slot = off[c] + (int)pos[e];
        csr[slot] = make_uint2((u32)r, __float_as_uint(nv));
    }
}

// ---------------- dense layers ----------------

__launch_bounds__(256)
__global__ void k_lin1(const float* __restrict__ x, const float* __restrict__ W,
                       const float* __restrict__ b, float* __restrict__ out) {
    __shared__ __align__(16) float xs[4 * FIN];     // 4 node rows
    int lane = threadIdx.x & 63;
    int sub  = threadIdx.x >> 6;
    float wrs[FIN];
    #pragma unroll
    for (int k = 0; k < FIN; k++) wrs[k] = W[k * HD + lane];
    float bias = b[lane];
    const int nchunk = NN / 4;
    for (int chunk = blockIdx.x; chunk < nchunk; chunk += gridDim.x) {
        int node0 = chunk * 4;
        __syncthreads();
        if (threadIdx.x < 128)
            ((float4*)xs)[threadIdx.x] =
                ((const float4*)(x + (size_t)node0 * FIN))[threadIdx.x];
        __syncthreads();
        float acc = bias;
        const float4* xv4 = (const float4*)(xs + sub * FIN);
        #pragma unroll
        for (int k = 0; k < FIN / 4; k++) {
            float4 xv = xv4[k];
            acc += xv.x * wrs[4*k] + xv.y * wrs[4*k+1] + xv.z * wrs[4*k+2] + xv.w * wrs[4*k+3];
        }
        out[(size_t)(node0 + sub) * HD + lane] = fmaxf(acc, 0.f);
    }
}

// out(bf16) = A @ W (no bias): [NN,64] @ [64,64]; f32 accumulate, bf16 store
__launch_bounds__(256)
__global__ void k_mm64(const float* __restrict__ A, const float* __restrict__ W,
                       __hip_bfloat16* __restrict__ out) {
    __shared__ __align__(16) float xs[4 * HD];
    int lane = threadIdx.x & 63;
    int sub  = threadIdx.x >> 6;
    float wrs[HD];
    #pragma unroll
    for (int k = 0; k < HD; k++) wrs[k] = W[k * HD + lane];
    const int nchunk = NN / 4;
    for (int chunk = blockIdx.x; chunk < nchunk; chunk += gridDim.x) {
        int node0 = chunk * 4;
        __syncthreads();
        if (threadIdx.x < 64)
            ((float4*)xs)[threadIdx.x] =
                ((const float4*)(A + (size_t)node0 * HD))[threadIdx.x];
        __syncthreads();
        float acc = 0.f;
        const float4* xv4 = (const float4*)(xs + sub * HD);
        #pragma unroll
        for (int k = 0; k < HD / 4; k++) {
            float4 xv = xv4[k];
            acc += xv.x * wrs[4*k] + xv.y * wrs[4*k+1] + xv.z * wrs[4*k+2] + xv.w * wrs[4*k+3];
        }
        out[(size_t)(node0 + sub) * HD + lane] = __float2bfloat16(acc);
    }
}

// out = relu(Ahat @ Bm + bias): 4 nodes per wave, 16 lanes per row (bf16x4 per lane).
// One gather instruction covers 4 edges (4 quarters x 16 lanes x 8B = 4 rows).
__launch_bounds__(256)
__global__ void k_agg(const u32* __restrict__ Bm2, const int* __restrict__ off,
                      const uint2* __restrict__ csr, const float* __restrict__ dinv,
                      const float* __restrict__ bias, float* __restrict__ outp) {
    int lane = threadIdx.x & 63;
    int wave = threadIdx.x >> 6;
    int q    = lane >> 4;                  // quarter: which of the wave's 4 nodes
    int fp   = lane & 15;                  // word-pair idx: features 4fp..4fp+3
    int node = blockIdx.x * 16 + wave * 4 + q;      // NN = 6250*16 exact
    int s = off[node], e = off[node + 1];
    int deg = e - s;
    float di = dinv[node];
    float sc = di * di;
    uint2 sw = *(const uint2*)(Bm2 + (size_t)node * 32 + fp * 2);
    float4 acc;
    acc.x = sc * u2lo(sw.x); acc.y = sc * u2hi(sw.x);
    acc.z = sc * u2lo(sw.y); acc.w = sc * u2hi(sw.y);
    for (int j = 0; __any(j < deg); j += 4) {
        #pragma unroll
        for (int k = 0; k < 4; k++) {
            uint2 c = csr[s + j + k];      // csr alloc'd +128: over-read in-bounds
            bool act = (j + k) < deg;
            u32 r     = act ? c.x : (u32)node;               // own row: L1-hot
            float wgt = act ? __uint_as_float(c.y) : 0.f;
            uint2 gw = *(const uint2*)(Bm2 + (size_t)r * 32 + fp * 2);
            acc.x += wgt * u2lo(gw.x); acc.y += wgt * u2hi(gw.x);
            acc.z += wgt * u2lo(gw.y); acc.w += wgt * u2hi(gw.y);
        }
    }
    float4 bv = *(const float4*)(bias + fp * 4);
    float4 o;
    o.x = fmaxf(acc.x + bv.x, 0.f);
    o.y = fmaxf(acc.y + bv.y, 0.f);
    o.z = fmaxf(acc.z + bv.z, 0.f);
    o.w = fmaxf(acc.w + bv.w, 0.f);
    *(float4*)(outp + (size_t)node * HD + fp * 4) = o;
}

// logits = H @ Wo + bo ; out = log_softmax(logits)
__launch_bounds__(256)
__global__ void k_out(const float* __restrict__ Hm, const float* __restrict__ W,
                      const float* __restrict__ b, float* __restrict__ outp) {
    __shared__ float Wl[HD * NC];
    __shared__ __align__(16) float hs[4 * HD];
    int lane = threadIdx.x & 63;
    int sub  = threadIdx.x >> 6;
    for (int i = threadIdx.x; i < HD * NC; i += 256) Wl[i] = W[i];
    int node0 = blockIdx.x * 4;
    if (threadIdx.x < 64)
        ((float4*)hs)[threadIdx.x] =
            ((const float4*)(Hm + (size_t)node0 * HD))[threadIdx.x];
    __syncthreads();
    float logit = -1e30f;
    if (lane < NC) {
        float acc = b[lane];
        #pragma unroll
        for (int k = 0; k < HD; k++) acc += hs[sub * HD + k] * Wl[k * NC + lane];
        logit = acc;
    }
    float m = logit;
    #pragma unroll
    for (int s = 32; s > 0; s >>= 1) m = fmaxf(m, __shfl_xor(m, s));
    float ex = (lane < NC) ? expf(logit - m) : 0.f;
    float sum = ex;
    #pragma unroll
    for (int s = 32; s > 0; s >>= 1) sum += __shfl_xor(sum, s);
    if (lane < NC) outp[(size_t)node0 * NC + sub * NC + lane] = (logit - m) - logf(sum);
}

// ---------------- launch ----------------

extern "C" void kernel_launch(void* const* d_in, const int* in_sizes, int n_in,
                              void* d_out, int out_size, void* d_ws, size_t ws_size,
                              hipStream_t stream) {
    const float* x   = (const float*)d_in[0];
    const int*   ei  = (const int*)  d_in[1];
    const float* ew  = (const float*)d_in[2];
    const float* Wf  = (const float*)d_in[3];
    const float* bf  = (const float*)d_in[4];
    const float* Wc1 = (const float*)d_in[5];
    const float* bc1 = (const float*)d_in[6];
    const float* Wc2 = (const float*)d_in[7];
    const float* bc2 = (const float*)d_in[8];
    const float* Wo  = (const float*)d_in[9];
    const float* bo  = (const float*)d_in[10];
    float* out = (float*)d_out;

    char* w = (char*)d_ws;
    auto alloc = [&](size_t bytes) {
        char* p = w;
        w += (bytes + 511) & ~(size_t)511;
        return p;
    };
    float* dinv = (float*)alloc((size_t)NN * 4);
    int*   off  = (int*)  alloc((size_t)(NN + 1) * 4);
    int*   bsum = (int*)  alloc((size_t)NB_SCAN * 4);
    uint2* csr  = (uint2*)alloc((size_t)(NE + 128) * 8);  // +128 pad for over-read
    float* bufA = (float*)alloc((size_t)NN * HD * 4);     // f32 h buffers
    char*  bufB = (char*) alloc((size_t)NN * HD * 4);     // bf16 table + overlays
    // overlays: dead before their hosts' first use (stream-ordered)
    u16* pos    = (u16*)bufA;                 // dead after k_fill; bufA first written by k_lin1
    ull* packed = (ull*)bufB;                 // dead after k_scan_local; bufB first written by k_mm64
    __hip_bfloat16* tbl = (__hip_bfloat16*)bufB;

    hipMemsetAsync(packed, 0, (size_t)NN * 8, stream);
    k_count     <<<(NE + 255) / 256, 256, 0, stream>>>(ei, ew, packed, pos);
    k_scan_local<<<NB_SCAN, 256, 0, stream>>>(packed, off, bsum, dinv);
    k_scan_bsum <<<1, 64, 0, stream>>>(bsum, off);
    k_scan_add  <<<NB_SCAN, 256, 0, stream>>>(off, bsum);
    k_fill      <<<(NE + 255) / 256, 256, 0, stream>>>(ei, ew, dinv, off, pos, csr);

    k_lin1 <<<1024, 256, 0, stream>>>(x, Wf, bf, bufA);
    k_mm64 <<<1024, 256, 0, stream>>>(bufA, Wc1, tbl);
    k_agg  <<<NN / 16, 256, 0, stream>>>((const u32*)tbl, off, csr, dinv, bc1, bufA);
    k_mm64 <<<1024, 256, 0, stream>>>(bufA, Wc2, tbl);
    k_agg  <<<NN / 16, 256, 0, stream>>>((const u32*)tbl, off, csr, dinv, bc2, bufA);
    k_out  <<<NN / 4, 256, 0, stream>>>(bufA, Wo, bo, out);
}

// Round 6
// 282.334 us; speedup vs baseline: 2.7983x; 1.3479x over previous
//
#include <hip/hip_runtime.h>
#include <hip/hip_bf16.h>
#include <cstdint>
#include <cstddef>

#define NN 100000
#define NE 1600000
#define FIN 128
#define HD 64
#define NC 40
#define NTILE (NN / 16)                      // 6250 MFMA row-tiles

#define SCAN_CHUNK 2048
#define NB_SCAN ((NN + SCAN_CHUNK - 1) / SCAN_CHUNK)   // 49

typedef unsigned long long ull;
typedef unsigned short u16;
typedef unsigned int u32;
typedef __attribute__((ext_vector_type(8))) short short8v;
typedef __attribute__((ext_vector_type(4))) float accf4;

__device__ __forceinline__ float u2lo(u32 u) { return __uint_as_float(u << 16); }
__device__ __forceinline__ float u2hi(u32 u) { return __uint_as_float(u & 0xFFFF0000u); }
__device__ __forceinline__ u16 f2b(float f) {            // RNE f32->bf16
    u32 u = __float_as_uint(f);
    return (u16)((u + 0x7FFFu + ((u >> 16) & 1u)) >> 16);
}

// ---------------- setup kernels ----------------

// one packed 32-bit atomic per edge: hi-12 = count, lo-20 = Q6.14 weight sum.
// returned old hi-12 = this edge's slot position within its target node.
__global__ void k_count(const int* __restrict__ ei, const float* __restrict__ ew,
                        u32* __restrict__ packed, u16* __restrict__ pos) {
    int e = blockIdx.x * 256 + threadIdx.x;
    if (e < NE) {
        int c = ei[NE + e];
        u32 fx = __float2uint_rn(ew[e] * 16384.0f);   // Q6.14
        u32 old = atomicAdd(&packed[c], (1u << 20) | fx);
        pos[e] = (u16)(old >> 20);
    }
}

// ---- two-level exclusive scan over counts (packed hi-12) -> off; also emits dinv ----

__launch_bounds__(256)
__global__ void k_scan_local(const u32* __restrict__ packed, int* __restrict__ off,
                             int* __restrict__ bsum, float* __restrict__ dinv) {
    __shared__ int wtot[4];
    int tid = threadIdx.x, lane = tid & 63, wid = tid >> 6;
    int base = blockIdx.x * SCAN_CHUNK + tid * 8;
    int v[8];
    int s = 0;
    #pragma unroll
    for (int i = 0; i < 8; i++) {
        if (base + i < NN) {
            u32 p = packed[base + i];
            v[i] = (int)(p >> 20);
            float deg = 1.0f + (float)(p & 0xFFFFFu) * (1.0f / 16384.0f);
            dinv[base + i] = rsqrtf(deg);
        } else v[i] = 0;
    }
    #pragma unroll
    for (int i = 0; i < 8; i++) s += v[i];
    int inc = s;
    #pragma unroll
    for (int d = 1; d < 64; d <<= 1) {
        int t = __shfl_up(inc, d);
        if (lane >= d) inc += t;
    }
    if (lane == 63) wtot[wid] = inc;
    __syncthreads();
    int wof = 0;
    #pragma unroll
    for (int k = 0; k < 4; k++) if (k < wid) wof += wtot[k];
    int run = wof + inc - s;
    #pragma unroll
    for (int i = 0; i < 8; i++) {
        if (base + i < NN) off[base + i] = run;
        run += v[i];
    }
    if (tid == 255) bsum[blockIdx.x] = wof + inc;
}

__global__ void k_scan_bsum(int* __restrict__ bsum, int* __restrict__ off) {
    int lane = threadIdx.x;
    int v = (lane < NB_SCAN) ? bsum[lane] : 0;
    int inc = v;
    #pragma unroll
    for (int d = 1; d < 64; d <<= 1) {
        int t = __shfl_up(inc, d);
        if (lane >= d) inc += t;
    }
    if (lane < NB_SCAN) bsum[lane] = inc - v;
    if (lane == 63) off[NN] = inc;
}

__launch_bounds__(256)
__global__ void k_scan_add(int* __restrict__ off, const int* __restrict__ bsum) {
    int carry = bsum[blockIdx.x];
    int base = blockIdx.x * SCAN_CHUNK + threadIdx.x * 8;
    if (base + 7 < NN) {
        int4* p = (int4*)(off + base);
        int4 a = p[0], b = p[1];
        a.x+=carry; a.y+=carry; a.z+=carry; a.w+=carry;
        b.x+=carry; b.y+=carry; b.z+=carry; b.w+=carry;
        p[0] = a; p[1] = b;
    } else {
        for (int i = 0; i < 8 && base + i < NN; i++) off[base + i] += carry;
    }
}

// atomic-free fill: slot = off[col] + pos[e]; one fused 8B store
__global__ void k_fill(const int* __restrict__ ei, const float* __restrict__ ew,
                       const float* __restrict__ dinv, const int* __restrict__ off,
                       const u16* __restrict__ pos, uint2* __restrict__ csr) {
    int e = blockIdx.x * 256 + threadIdx.x;
    if (e < NE) {
        int r = ei[e], c = ei[NE + e];
        float nv = dinv[r] * ew[e] * dinv[c];
        int slot = off[c] + (int)pos[e];
        csr[slot] = make_uint2((u32)r, __float_as_uint(nv));
    }
}

// ---------------- dense layers (MFMA bf16) ----------------

// h(bf16) = relu(x @ W + b): [NN,128]@[128,64]; one wave per 16-node tile
__launch_bounds__(256)
__global__ void k_lin1(const float* __restrict__ x, const float* __restrict__ W,
                       const float* __restrict__ b, u16* __restrict__ out) {
    int lane = threadIdx.x & 63;
    int tile = blockIdx.x * 4 + (threadIdx.x >> 6);
    if (tile >= NTILE) return;
    int row = lane & 15;                   // A-row (node) / B-col (feature)
    int kg  = lane >> 4;                   // k-group
    short8v bW[4][4];                      // [ktile][coltile]
    #pragma unroll
    for (int kt = 0; kt < 4; kt++)
        #pragma unroll
        for (int ct = 0; ct < 4; ct++)
            #pragma unroll
            for (int j = 0; j < 8; j++)
                bW[kt][ct][j] = (short)f2b(W[(kt*32 + kg*8 + j) * HD + ct*16 + row]);
    int node0 = tile * 16;
    const float* xr = x + (size_t)(node0 + row) * FIN + kg * 8;
    float4 xa[4][2];
    #pragma unroll
    for (int kt = 0; kt < 4; kt++) {
        xa[kt][0] = *(const float4*)(xr + kt*32);
        xa[kt][1] = *(const float4*)(xr + kt*32 + 4);
    }
    short8v af[4];
    #pragma unroll
    for (int kt = 0; kt < 4; kt++) {
        af[kt][0] = (short)f2b(xa[kt][0].x); af[kt][1] = (short)f2b(xa[kt][0].y);
        af[kt][2] = (short)f2b(xa[kt][0].z); af[kt][3] = (short)f2b(xa[kt][0].w);
        af[kt][4] = (short)f2b(xa[kt][1].x); af[kt][5] = (short)f2b(xa[kt][1].y);
        af[kt][6] = (short)f2b(xa[kt][1].z); af[kt][7] = (short)f2b(xa[kt][1].w);
    }
    accf4 acc[4] = {};
    #pragma unroll
    for (int kt = 0; kt < 4; kt++)
        #pragma unroll
        for (int ct = 0; ct < 4; ct++)
            acc[ct] = __builtin_amdgcn_mfma_f32_16x16x32_bf16(af[kt], bW[kt][ct], acc[ct], 0, 0, 0);
    #pragma unroll
    for (int ct = 0; ct < 4; ct++) {
        float bias = b[ct*16 + row];
        #pragma unroll
        for (int r = 0; r < 4; r++) {
            float v = fmaxf(acc[ct][r] + bias, 0.f);
            out[(size_t)(node0 + kg*4 + r) * HD + ct*16 + row] = f2b(v);
        }
    }
}

// out(bf16) = A(bf16) @ W (no bias): [NN,64]@[64,64]
__launch_bounds__(256)
__global__ void k_mm64(const u16* __restrict__ A, const float* __restrict__ W,
                       u16* __restrict__ out) {
    int lane = threadIdx.x & 63;
    int tile = blockIdx.x * 4 + (threadIdx.x >> 6);
    if (tile >= NTILE) return;
    int row = lane & 15;
    int kg  = lane >> 4;
    short8v bW[2][4];
    #pragma unroll
    for (int kt = 0; kt < 2; kt++)
        #pragma unroll
        for (int ct = 0; ct < 4; ct++)
            #pragma unroll
            for (int j = 0; j < 8; j++)
                bW[kt][ct][j] = (short)f2b(W[(kt*32 + kg*8 + j) * HD + ct*16 + row]);
    int node0 = tile * 16;
    const u16* ar = A + (size_t)(node0 + row) * HD + kg * 8;
    short8v af0 = *(const short8v*)(ar);
    short8v af1 = *(const short8v*)(ar + 32);
    accf4 acc[4] = {};
    #pragma unroll
    for (int ct = 0; ct < 4; ct++) {
        acc[ct] = __builtin_amdgcn_mfma_f32_16x16x32_bf16(af0, bW[0][ct], acc[ct], 0, 0, 0);
        acc[ct] = __builtin_amdgcn_mfma_f32_16x16x32_bf16(af1, bW[1][ct], acc[ct], 0, 0, 0);
    }
    #pragma unroll
    for (int ct = 0; ct < 4; ct++)
        #pragma unroll
        for (int r = 0; r < 4; r++)
            out[(size_t)(node0 + kg*4 + r) * HD + ct*16 + row] = f2b(acc[ct][r]);
}

// out(bf16) = relu(Ahat @ Bm + bias): 4 nodes/wave, 16 lanes/row, csr prefetch
__launch_bounds__(256)
__global__ void k_agg(const u32* __restrict__ Bm2, const int* __restrict__ off,
                      const uint2* __restrict__ csr, const float* __restrict__ dinv,
                      const float* __restrict__ bias, uint2* __restrict__ outp) {
    int lane = threadIdx.x & 63;
    int wave = threadIdx.x >> 6;
    int q    = lane >> 4;
    int fp   = lane & 15;
    int node = blockIdx.x * 16 + wave * 4 + q;
    int s = off[node], e = off[node + 1];
    int deg = e - s;
    float di = dinv[node];
    float sc = di * di;
    uint2 sw = *(const uint2*)(Bm2 + (size_t)node * 32 + fp * 2);
    float4 acc;
    acc.x = sc * u2lo(sw.x); acc.y = sc * u2hi(sw.x);
    acc.z = sc * u2lo(sw.y); acc.w = sc * u2hi(sw.y);
    uint2 c0 = csr[s+0], c1 = csr[s+1], c2 = csr[s+2], c3 = csr[s+3];
    for (int j = 0; __any(j < deg); j += 4) {
        // prefetch next chunk (csr +128 pad keeps over-reads in-bounds)
        uint2 n0 = csr[s+j+4], n1 = csr[s+j+5], n2 = csr[s+j+6], n3 = csr[s+j+7];
        bool a0 = (j+0) < deg; u32 r0 = a0 ? c0.x : (u32)node; float w0 = a0 ? __uint_as_float(c0.y) : 0.f;
        bool a1 = (j+1) < deg; u32 r1 = a1 ? c1.x : (u32)node; float w1 = a1 ? __uint_as_float(c1.y) : 0.f;
        bool a2 = (j+2) < deg; u32 r2 = a2 ? c2.x : (u32)node; float w2 = a2 ? __uint_as_float(c2.y) : 0.f;
        bool a3 = (j+3) < deg; u32 r3 = a3 ? c3.x : (u32)node; float w3 = a3 ? __uint_as_float(c3.y) : 0.f;
        uint2 g0 = *(const uint2*)(Bm2 + (size_t)r0 * 32 + fp * 2);
        uint2 g1 = *(const uint2*)(Bm2 + (size_t)r1 * 32 + fp * 2);
        uint2 g2 = *(const uint2*)(Bm2 + (size_t)r2 * 32 + fp * 2);
        uint2 g3 = *(const uint2*)(Bm2 + (size_t)r3 * 32 + fp * 2);
        acc.x += w0 * u2lo(g0.x) + w1 * u2lo(g1.x);
        acc.y += w0 * u2hi(g0.x) + w1 * u2hi(g1.x);
        acc.z += w0 * u2lo(g0.y) + w1 * u2lo(g1.y);
        acc.w += w0 * u2hi(g0.y) + w1 * u2hi(g1.y);
        acc.x += w2 * u2lo(g2.x) + w3 * u2lo(g3.x);
        acc.y += w2 * u2hi(g2.x) + w3 * u2hi(g3.x);
        acc.z += w2 * u2lo(g2.y) + w3 * u2lo(g3.y);
        acc.w += w2 * u2hi(g2.y) + w3 * u2hi(g3.y);
        c0 = n0; c1 = n1; c2 = n2; c3 = n3;
    }
    float4 bv = *(const float4*)(bias + fp * 4);
    uint2 ov;
    ov.x = (u32)f2b(fmaxf(acc.x + bv.x, 0.f)) | ((u32)f2b(fmaxf(acc.y + bv.y, 0.f)) << 16);
    ov.y = (u32)f2b(fmaxf(acc.z + bv.z, 0.f)) | ((u32)f2b(fmaxf(acc.w + bv.w, 0.f)) << 16);
    outp[(size_t)node * 16 + fp] = ov;
}

// logits = H(bf16) @ Wo + bo ; out = log_softmax(logits)
__launch_bounds__(256)
__global__ void k_out(const u32* __restrict__ Hm, const float* __restrict__ W,
                      const float* __restrict__ b, float* __restrict__ outp) {
    __shared__ float Wl[HD * NC];
    __shared__ __align__(16) float hs[4 * HD];
    int lane = threadIdx.x & 63;
    int sub  = threadIdx.x >> 6;
    for (int i = threadIdx.x; i < HD * NC; i += 256) Wl[i] = W[i];
    int node0 = blockIdx.x * 4;
    if (threadIdx.x < 64) {
        int row = threadIdx.x >> 4, g = threadIdx.x & 15;
        uint2 v = *(const uint2*)(Hm + (size_t)(node0 + row) * 32 + g * 2);
        hs[row*64 + g*4 + 0] = u2lo(v.x);
        hs[row*64 + g*4 + 1] = u2hi(v.x);
        hs[row*64 + g*4 + 2] = u2lo(v.y);
        hs[row*64 + g*4 + 3] = u2hi(v.y);
    }
    __syncthreads();
    float logit = -1e30f;
    if (lane < NC) {
        float acc = b[lane];
        #pragma unroll
        for (int k = 0; k < HD; k++) acc += hs[sub * HD + k] * Wl[k * NC + lane];
        logit = acc;
    }
    float m = logit;
    #pragma unroll
    for (int s = 32; s > 0; s >>= 1) m = fmaxf(m, __shfl_xor(m, s));
    float ex = (lane < NC) ? expf(logit - m) : 0.f;
    float sum = ex;
    #pragma unroll
    for (int s = 32; s > 0; s >>= 1) sum += __shfl_xor(sum, s);
    if (lane < NC) outp[(size_t)node0 * NC + sub * NC + lane] = (logit - m) - logf(sum);
}

// ---------------- launch ----------------

extern "C" void kernel_launch(void* const* d_in, const int* in_sizes, int n_in,
                              void* d_out, int out_size, void* d_ws, size_t ws_size,
                              hipStream_t stream) {
    const float* x   = (const float*)d_in[0];
    const int*   ei  = (const int*)  d_in[1];
    const float* ew  = (const float*)d_in[2];
    const float* Wf  = (const float*)d_in[3];
    const float* bf  = (const float*)d_in[4];
    const float* Wc1 = (const float*)d_in[5];
    const float* bc1 = (const float*)d_in[6];
    const float* Wc2 = (const float*)d_in[7];
    const float* bc2 = (const float*)d_in[8];
    const float* Wo  = (const float*)d_in[9];
    const float* bo  = (const float*)d_in[10];
    float* out = (float*)d_out;

    char* w = (char*)d_ws;
    auto alloc = [&](size_t bytes) {
        char* p = w;
        w += (bytes + 511) & ~(size_t)511;
        return p;
    };
    float* dinv = (float*)alloc((size_t)NN * 4);
    int*   off  = (int*)  alloc((size_t)(NN + 1) * 4);
    int*   bsum = (int*)  alloc((size_t)NB_SCAN * 4);
    uint2* csr  = (uint2*)alloc((size_t)(NE + 128) * 8);  // +128 pad for over-read
    u16*   hA   = (u16*)  alloc((size_t)NN * HD * 2);     // bf16 buffers
    u16*   hB   = (u16*)  alloc((size_t)NN * HD * 2);
    // overlays (dead before hosts' first write, stream-ordered):
    u16* pos    = (u16*)hA;        // dead after k_fill; hA first written by k_lin1
    u32* packed = (u32*)hB;        // dead after k_scan_local; hB first written by k_mm64

    hipMemsetAsync(packed, 0, (size_t)NN * 4, stream);
    k_count     <<<(NE + 255) / 256, 256, 0, stream>>>(ei, ew, packed, pos);
    k_scan_local<<<NB_SCAN, 256, 0, stream>>>(packed, off, bsum, dinv);
    k_scan_bsum <<<1, 64, 0, stream>>>(bsum, off);
    k_scan_add  <<<NB_SCAN, 256, 0, stream>>>(off, bsum);
    k_fill      <<<(NE + 255) / 256, 256, 0, stream>>>(ei, ew, dinv, off, pos, csr);

    int mmblocks = (NTILE + 3) / 4;
    k_lin1 <<<mmblocks, 256, 0, stream>>>(x, Wf, bf, hA);
    k_mm64 <<<mmblocks, 256, 0, stream>>>(hA, Wc1, hB);
    k_agg  <<<NN / 16, 256, 0, stream>>>((const u32*)hB, off, csr, dinv, bc1, (uint2*)hA);
    k_mm64 <<<mmblocks, 256, 0, stream>>>(hA, Wc2, hB);
    k_agg  <<<NN / 16, 256, 0, stream>>>((const u32*)hB, off, csr, dinv, bc2, (uint2*)hA);
    k_out  <<<NN / 4, 256, 0, stream>>>((const u32*)hA, Wo, bo, out);
}